// Round 4
// baseline (471.545 us; speedup 1.0000x reference)
//
#include <hip/hip_runtime.h>
#include <stdint.h>

#define NN 100000
#define NE 1600000
#define NR 4
#define NK (NN * NR)      // 400000 (dst,rel) keys
#define FD 128
#define KT 640            // 512 (rel) + 128 (root)
#define NQ 1024
#define HIDN 256

#define NB 391            // dst buckets of 256 nodes
#define BSH 8
#define CAPB 8192         // fixed bpack capacity per bucket (avg 4096, sigma ~64)
#define EPB 2048
#define NBLK1 ((NE + EPB - 1) / EPB)   // 782
#define NBLKF ((NN + 127) / 128)       // 782

using u16 = unsigned short;
using u32 = unsigned int;
typedef __attribute__((ext_vector_type(8))) __bf16 bf16x8;
typedef __attribute__((ext_vector_type(4))) float f32x4;

__device__ __forceinline__ u16 f2b(float f) {
    u32 u = __builtin_bit_cast(u32, f);
    u32 r = u + 0x7FFFu + ((u >> 16) & 1u);   // round-to-nearest-even
    return (u16)(r >> 16);
}
__device__ __forceinline__ float b2f(u16 h) {
    u32 u = ((u32)h) << 16;
    return __builtin_bit_cast(float, u);
}
__device__ __forceinline__ u32 pack2(float a, float b) {
    return (u32)f2b(a) | ((u32)f2b(b) << 16);
}

// ---------- phase 1: bucket scatter into fixed-capacity bucket-major segments ----------
__global__ __launch_bounds__(256) void bucket_scatter(const int* __restrict__ ei,
                                                      const int* __restrict__ et,
                                                      int* __restrict__ bcnt,
                                                      u32* __restrict__ bpack) {
    __shared__ int hist[NB];
    __shared__ int base[NB];
    int t = threadIdx.x;
    for (int i = t; i < NB; i += 256) hist[i] = 0;
    __syncthreads();
    int e0 = blockIdx.x * EPB;
    int rank[8];
    u32 pk[8];
    int bk[8];
#pragma unroll
    for (int j = 0; j < 8; ++j) {
        int e = e0 + j * 256 + t;
        bk[j] = -1;
        if (e < NE) {
            int src = __builtin_nontemporal_load(ei + e);
            int dst = __builtin_nontemporal_load(ei + NE + e);
            int r   = __builtin_nontemporal_load(et + e);
            bk[j] = dst >> BSH;
            pk[j] = (u32)src | ((u32)r << 17) | ((u32)(dst & 255) << 19);
            rank[j] = atomicAdd(&hist[bk[j]], 1);
        }
    }
    __syncthreads();
    for (int i = t; i < NB; i += 256) {
        int h = hist[i];
        base[i] = h ? atomicAdd(&bcnt[i], h) : 0;
    }
    __syncthreads();
#pragma unroll
    for (int j = 0; j < 8; ++j)
        if (bk[j] >= 0) bpack[(size_t)bk[j] * CAPB + base[bk[j]] + rank[j]] = pk[j];
}

// ---------- exclusive scan of bucket counts ----------
__global__ __launch_bounds__(512) void bucket_scan(const int* __restrict__ bcnt,
                                                   int* __restrict__ bbase,
                                                   int* __restrict__ offs4) {
    __shared__ int sm[512];
    int t = threadIdx.x;
    int v = (t < NB) ? bcnt[t] : 0;
    sm[t] = v;
    __syncthreads();
    for (int o2 = 1; o2 < 512; o2 <<= 1) {
        int n = (t >= o2) ? sm[t - o2] : 0;
        __syncthreads();
        sm[t] += n;
        __syncthreads();
    }
    if (t < NB) bbase[t] = sm[t] - v;
    if (t == 0) offs4[NK] = NE;
}

// ---------- phase 2: per-bucket key sort; also emits offs4 (the (dst,rel) CSR) ----------
__global__ __launch_bounds__(256) void key_scatter(const int* __restrict__ bcnt,
                                                   const int* __restrict__ bbase,
                                                   const u32* __restrict__ bpack,
                                                   int* __restrict__ offs4,
                                                   int* __restrict__ spack) {
    __shared__ int hist[1024];
    __shared__ int sm[256];
    int b = blockIdx.x, t = threadIdx.x;
    int cnt = bcnt[b];
    int gbase = bbase[b];
    const u32* seg = bpack + (size_t)b * CAPB;
#pragma unroll
    for (int j = 0; j < 4; ++j) hist[t + j * 256] = 0;
    __syncthreads();
    for (int i = t; i < cnt; i += 256) {
        u32 pk = seg[i];
        atomicAdd(&hist[pk >> 17], 1);
    }
    __syncthreads();
    int t4 = t * 4;
    int h0 = hist[t4], h1 = hist[t4 + 1], h2 = hist[t4 + 2], h3 = hist[t4 + 3];
    int s = h0 + h1 + h2 + h3;
    sm[t] = s;
    __syncthreads();
    for (int o2 = 1; o2 < 256; o2 <<= 1) {
        int n = (t >= o2) ? sm[t - o2] : 0;
        __syncthreads();
        sm[t] += n;
        __syncthreads();
    }
    int e0 = gbase + sm[t] - s;
    int e1 = e0 + h0, e2 = e1 + h1, e3 = e2 + h2;
    int k0 = b << 10;
    if (k0 + t4 + 0 < NK) offs4[k0 + t4 + 0] = e0;
    if (k0 + t4 + 1 < NK) offs4[k0 + t4 + 1] = e1;
    if (k0 + t4 + 2 < NK) offs4[k0 + t4 + 2] = e2;
    if (k0 + t4 + 3 < NK) offs4[k0 + t4 + 3] = e3;
    hist[t4] = e0; hist[t4 + 1] = e1; hist[t4 + 2] = e2; hist[t4 + 3] = e3;
    __syncthreads();
    for (int i = t; i < cnt; i += 256) {
        u32 pk = seg[i];
        int pos = atomicAdd(&hist[pk >> 17], 1);
        spack[pos] = (int)(pk & 0x1FFFFu);
    }
}

// ---------- conversions / weight prep ----------
__global__ __launch_bounds__(256) void cvt_bf16(const float* __restrict__ in,
                                                u16* __restrict__ outp, int n) {
    int i = blockIdx.x * 256 + threadIdx.x;
    int idx = i * 4;
    if (idx + 3 >= n) {
        for (int j = idx; j < n; ++j) outp[j] = f2b(in[j]);
        return;
    }
    float4 v = *(const float4*)(in + idx);
    u32 lo = (u32)f2b(v.x) | ((u32)f2b(v.y) << 16);
    u32 hi = (u32)f2b(v.z) | ((u32)f2b(v.w) << 16);
    *(uint2*)(outp + idx) = make_uint2(lo, hi);
}

__global__ __launch_bounds__(256) void prep_B(const float* __restrict__ Wrel,
                                              const float* __restrict__ Wroot,
                                              u16* __restrict__ Bt) {
    int i = blockIdx.x * 256 + threadIdx.x;
    if (i >= FD * KT) return;
    int k = i % KT;
    int o = i / KT;
    float v = (k < 512) ? Wrel[(size_t)k * FD + o] : Wroot[(size_t)(k - 512) * FD + o];
    Bt[i] = f2b(v);
}

// ---------- fused layer-1: gather->LDS (swizzled) -> MFMA, no A1 materialization ----------
// Block = 128 rows. 3 K-chunks: {rel0,rel1}=cols 0..255, {rel2,rel3}=256..511, root=512..639.
// LDS tile 128 x 256 bf16 (64 KB), XOR swizzle byte ^= (row&7)<<4 (conflict-free writes + b128 reads).
__global__ __launch_bounds__(256) void rgcn_l1_fused(const int* __restrict__ offs4,
                                                     const int* __restrict__ spack,
                                                     const u32* __restrict__ fp,   // xh as u32[node][64]
                                                     const u16* __restrict__ Bt,
                                                     const float* __restrict__ bias,
                                                     u16* __restrict__ h1) {
    __shared__ u16 As[32768];   // 64 KB
    char* lds = (char*)As;
    int tid = threadIdx.x;
    int wid = tid >> 6, lane = tid & 63;
    int wm = wid >> 1, wn = wid & 1;
    int lr = lane & 15, hi = lane >> 4;
    int row0 = blockIdx.x * 128;
    int g0 = row0 + wid * 32;          // this wave's first node
    bool waveActive = (g0 < NN);

    // Preload this wave's 129 CSR offsets into 2 VGPRs + 1 scalar.
    int v0 = 0, v1 = 0, o_last = 0;
    if (waveActive) {
        const int* ob = offs4 + (size_t)g0 * 4;
        v0 = ob[2 * lane];
        v1 = ob[2 * lane + 1];
        o_last = offs4[((size_t)g0 + 32) * 4];
    }

    f32x4 acc[4][4];
#pragma unroll
    for (int i = 0; i < 4; ++i)
#pragma unroll
        for (int j = 0; j < 4; ++j) acc[i][j] = (f32x4){0.f, 0.f, 0.f, 0.f};

    for (int c = 0; c < 3; ++c) {
        // ---- stage phase ----
        if (c < 2) {
            for (int rr = 0; rr < 32; ++rr) {
                int row = wid * 32 + rr;
                int g = row0 + row;
                u32 w0p = 0, w1p = 0;
                if (g < NN) {
                    int ls = 2 * rr + c;
                    int o0v = __builtin_amdgcn_readlane(v0, ls);
                    int o1v = __builtin_amdgcn_readlane(v1, ls);
                    int o2v = (ls + 1 < 64) ? __builtin_amdgcn_readlane(v0, ls + 1) : o_last;
                    float a00 = 0, a01 = 0, a10 = 0, a11 = 0;
                    int lim = o2v - 1;
                    for (int i = o0v; i < o2v; i += 8) {
                        int i1 = i + 1 > lim ? lim : i + 1;
                        int i2 = i + 2 > lim ? lim : i + 2;
                        int i3 = i + 3 > lim ? lim : i + 3;
                        int i4 = i + 4 > lim ? lim : i + 4;
                        int i5 = i + 5 > lim ? lim : i + 5;
                        int i6 = i + 6 > lim ? lim : i + 6;
                        int i7 = i + 7 > lim ? lim : i + 7;
                        int p0 = spack[i];  int p1 = spack[i1]; int p2 = spack[i2]; int p3 = spack[i3];
                        int p4 = spack[i4]; int p5 = spack[i5]; int p6 = spack[i6]; int p7 = spack[i7];
                        u32 x0 = fp[(size_t)p0 * 64 + lane];
                        u32 x1 = fp[(size_t)p1 * 64 + lane];
                        u32 x2 = fp[(size_t)p2 * 64 + lane];
                        u32 x3 = fp[(size_t)p3 * 64 + lane];
                        u32 x4 = fp[(size_t)p4 * 64 + lane];
                        u32 x5 = fp[(size_t)p5 * 64 + lane];
                        u32 x6 = fp[(size_t)p6 * 64 + lane];
                        u32 x7 = fp[(size_t)p7 * 64 + lane];
#define EDGE_ACC(J, XV)                                              \
    if (i + (J) < o2v) {                                             \
        float f0 = b2f((u16)((XV) & 0xFFFFu));                       \
        float f1 = b2f((u16)((XV) >> 16));                           \
        if (i + (J) < o1v) { a00 += f0; a01 += f1; }                 \
        else               { a10 += f0; a11 += f1; }                 \
    }
                        EDGE_ACC(0, x0) EDGE_ACC(1, x1) EDGE_ACC(2, x2) EDGE_ACC(3, x3)
                        EDGE_ACC(4, x4) EDGE_ACC(5, x5) EDGE_ACC(6, x6) EDGE_ACC(7, x7)
#undef EDGE_ACC
                    }
                    int d0 = o1v - o0v, d1 = o2v - o1v;
                    float s0 = 1.0f / (float)(d0 > 1 ? d0 : 1);
                    float s1 = 1.0f / (float)(d1 > 1 ? d1 : 1);
                    w0p = pack2(a00 * s0, a01 * s0);
                    w1p = pack2(a10 * s1, a11 * s1);
                }
                int rb = row * 512;
                int sw = (row & 7) << 4;
                *(u32*)(lds + rb + ((lane * 4) ^ sw)) = w0p;
                *(u32*)(lds + rb + ((256 + lane * 4) ^ sw)) = w1p;
            }
        } else {
            for (int rr = 0; rr < 32; ++rr) {
                int row = wid * 32 + rr;
                int g = row0 + row;
                u32 v = (g < NN) ? fp[(size_t)g * 64 + lane] : 0;
                *(u32*)(lds + row * 512 + ((lane * 4) ^ ((row & 7) << 4))) = v;
            }
        }
        __syncthreads();
        // ---- MFMA phase ----
        int nkk = (c < 2) ? 8 : 4;
        for (int kk = 0; kk < nkk; ++kk) {
            int kg = c * 256 + kk * 32 + hi * 8;   // global K for Bt
            int kl = (kk * 32 + hi * 8) * 2;       // local LDS byte col
            bf16x8 bfr[4], afr[4];
#pragma unroll
            for (int ni = 0; ni < 4; ++ni) {
                int col = wn * 64 + ni * 16 + lr;
                bfr[ni] = *reinterpret_cast<const bf16x8*>(Bt + (size_t)col * KT + kg);
            }
#pragma unroll
            for (int mi = 0; mi < 4; ++mi) {
                int row = wm * 64 + mi * 16 + lr;
                afr[mi] = *reinterpret_cast<const bf16x8*>(lds + row * 512 + (kl ^ ((row & 7) << 4)));
            }
#pragma unroll
            for (int mi = 0; mi < 4; ++mi)
#pragma unroll
                for (int ni = 0; ni < 4; ++ni)
                    acc[mi][ni] = __builtin_amdgcn_mfma_f32_16x16x32_bf16(afr[mi], bfr[ni], acc[mi][ni], 0, 0, 0);
        }
        __syncthreads();
    }
    // ---- epilogue: bias + relu + bf16 store ----
#pragma unroll
    for (int mi = 0; mi < 4; ++mi) {
#pragma unroll
        for (int ni = 0; ni < 4; ++ni) {
            int col = wn * 64 + ni * 16 + lr;
            float bv = bias[col];
#pragma unroll
            for (int rg = 0; rg < 4; ++rg) {
                int row = row0 + wm * 64 + mi * 16 + hi * 4 + rg;
                if (row < NN) {
                    float v = fmaxf(acc[mi][ni][rg] + bv, 0.f);
                    h1[(size_t)row * FD + col] = f2b(v);
                }
            }
        }
    }
}

// ---------- layer-2 aggregation over the 2048 query nodes ----------
__global__ __launch_bounds__(256) void agg_q(const int* __restrict__ offs4,
                                             const int* __restrict__ spack,
                                             const u32* __restrict__ fp,   // h1 as u32[node][64]
                                             u16* __restrict__ Aout,
                                             const int* __restrict__ nest,
                                             const int* __restrict__ food) {
    int wid = threadIdx.x >> 6, lane = threadIdx.x & 63;
    int row = blockIdx.x * 4 + wid;
    if (row >= 2 * NQ) return;
    int node = (row < NQ) ? nest[row] : food[row - NQ];

    int o0 = offs4[node * 4 + 0];
    int o1 = offs4[node * 4 + 1];
    int o2 = offs4[node * 4 + 2];
    int o3 = offs4[node * 4 + 3];
    int o4 = offs4[node * 4 + 4];

    float a00 = 0, a01 = 0, a10 = 0, a11 = 0, a20 = 0, a21 = 0, a30 = 0, a31 = 0;

#define ACCJ(IDX, V)                                             \
    {                                                            \
        float w0 = b2f((u16)((V) & 0xFFFFu));                    \
        float w1 = b2f((u16)((V) >> 16));                        \
        int _ix = (IDX);                                         \
        if (_ix < o1)      { a00 += w0; a01 += w1; }             \
        else if (_ix < o2) { a10 += w0; a11 += w1; }             \
        else if (_ix < o3) { a20 += w0; a21 += w1; }             \
        else               { a30 += w0; a31 += w1; }             \
    }

    int i = o0;
    for (; i + 8 <= o4; i += 8) {
        int p0 = spack[i + 0], p1 = spack[i + 1], p2 = spack[i + 2], p3 = spack[i + 3];
        int p4 = spack[i + 4], p5 = spack[i + 5], p6 = spack[i + 6], p7 = spack[i + 7];
        u32 v0 = fp[(size_t)p0 * 64 + lane];
        u32 v1 = fp[(size_t)p1 * 64 + lane];
        u32 v2 = fp[(size_t)p2 * 64 + lane];
        u32 v3 = fp[(size_t)p3 * 64 + lane];
        u32 v4 = fp[(size_t)p4 * 64 + lane];
        u32 v5 = fp[(size_t)p5 * 64 + lane];
        u32 v6 = fp[(size_t)p6 * 64 + lane];
        u32 v7 = fp[(size_t)p7 * 64 + lane];
        ACCJ(i + 0, v0); ACCJ(i + 1, v1); ACCJ(i + 2, v2); ACCJ(i + 3, v3);
        ACCJ(i + 4, v4); ACCJ(i + 5, v5); ACCJ(i + 6, v6); ACCJ(i + 7, v7);
    }
    for (; i < o4; ++i) {
        int p = spack[i];
        u32 v = fp[(size_t)p * 64 + lane];
        ACCJ(i, v);
    }
#undef ACCJ

    int d0 = o1 - o0, d1 = o2 - o1, d2 = o3 - o2, d3 = o4 - o3;
    float s0 = 1.0f / (float)(d0 > 1 ? d0 : 1);
    float s1 = 1.0f / (float)(d1 > 1 ? d1 : 1);
    float s2 = 1.0f / (float)(d2 > 1 ? d2 : 1);
    float s3 = 1.0f / (float)(d3 > 1 ? d3 : 1);
    size_t ob = (size_t)row * KT + lane * 2;
    u16* Ao = Aout + ob;
    *(u32*)(Ao + 0)   = pack2(a00 * s0, a01 * s0);
    *(u32*)(Ao + 128) = pack2(a10 * s1, a11 * s1);
    *(u32*)(Ao + 256) = pack2(a20 * s2, a21 * s2);
    *(u32*)(Ao + 384) = pack2(a30 * s3, a31 * s3);
    *(u32*)(Ao + 512) = fp[(size_t)node * 64 + lane];   // root concat
}

// ---------- GEMM for layer 2 (M=2048): C = A[M,640] @ Bt^T + bias ----------
__global__ __launch_bounds__(256) void gemm640(const u16* __restrict__ A,
                                               const u16* __restrict__ Bt,
                                               const float* __restrict__ bias,
                                               float* __restrict__ Cout, int M) {
    __shared__ u16 As[128][72];
    int tid = threadIdx.x;
    int wid = tid >> 6, lane = tid & 63;
    int wm = wid >> 1, wn = wid & 1;
    int lr = lane & 15, hi = lane >> 4;
    int row0 = blockIdx.x * 128;

    f32x4 acc[4][4];
#pragma unroll
    for (int i = 0; i < 4; ++i)
#pragma unroll
        for (int j = 0; j < 4; ++j) acc[i][j] = (f32x4){0.f, 0.f, 0.f, 0.f};

    for (int t = 0; t < KT / 64; ++t) {
#pragma unroll
        for (int it = 0; it < 4; ++it) {
            int r = (tid >> 3) + it * 32;
            int seg = tid & 7;
            int grow = row0 + r;
            uint4 v = make_uint4(0, 0, 0, 0);
            if (grow < M)
                v = *reinterpret_cast<const uint4*>(A + (size_t)grow * KT + t * 64 + seg * 8);
            *reinterpret_cast<uint4*>(&As[r][seg * 8]) = v;
        }
        __syncthreads();
#pragma unroll
        for (int kk = 0; kk < 2; ++kk) {
            int k0 = t * 64 + kk * 32 + hi * 8;
            bf16x8 afr[4], bfr[4];
#pragma unroll
            for (int ni = 0; ni < 4; ++ni) {
                int col = wn * 64 + ni * 16 + lr;
                bfr[ni] = *reinterpret_cast<const bf16x8*>(Bt + (size_t)col * KT + k0);
            }
#pragma unroll
            for (int mi = 0; mi < 4; ++mi)
                afr[mi] = *reinterpret_cast<const bf16x8*>(&As[wm * 64 + mi * 16 + lr][kk * 32 + hi * 8]);
#pragma unroll
            for (int mi = 0; mi < 4; ++mi)
#pragma unroll
                for (int ni = 0; ni < 4; ++ni)
                    acc[mi][ni] = __builtin_amdgcn_mfma_f32_16x16x32_bf16(afr[mi], bfr[ni], acc[mi][ni], 0, 0, 0);
        }
        __syncthreads();
    }
#pragma unroll
    for (int mi = 0; mi < 4; ++mi) {
#pragma unroll
        for (int ni = 0; ni < 4; ++ni) {
            int col = wn * 64 + ni * 16 + lr;
            float bv = bias[col];
#pragma unroll
            for (int rg = 0; rg < 4; ++rg) {
                int row = row0 + wm * 64 + mi * 16 + hi * 4 + rg;
                if (row < M) Cout[(size_t)row * FD + col] = acc[mi][ni][rg] + bv;
            }
        }
    }
}

// ---------- final FC ----------
__global__ __launch_bounds__(256) void fc_kernel(const float* __restrict__ h2q,
                                                 const float* __restrict__ Wfc,
                                                 const float* __restrict__ bfc,
                                                 float* __restrict__ out) {
    __shared__ float comb[2 * FD];
    int q = blockIdx.x, t = threadIdx.x;
    if (t < FD) comb[t] = h2q[(size_t)q * FD + t];
    else comb[t] = h2q[(size_t)(NQ + q) * FD + (t - FD)];
    __syncthreads();
    float s = bfc[t];
#pragma unroll 4
    for (int k = 0; k < 2 * FD; ++k) s += comb[k] * Wfc[(size_t)k * HIDN + t];
    out[(size_t)q * HIDN + t] = fmaxf(s, 0.f);
}

extern "C" void kernel_launch(void* const* d_in, const int* in_sizes, int n_in,
                              void* d_out, int out_size, void* d_ws, size_t ws_size,
                              hipStream_t stream) {
    const float* x      = (const float*)d_in[0];
    const int*   ei     = (const int*)d_in[1];
    const int*   et     = (const int*)d_in[2];
    const int*   nest   = (const int*)d_in[3];
    const int*   food   = (const int*)d_in[4];
    const float* Wrel1  = (const float*)d_in[5];
    const float* Wroot1 = (const float*)d_in[6];
    const float* b1     = (const float*)d_in[7];
    const float* Wrel2  = (const float*)d_in[8];
    const float* Wroot2 = (const float*)d_in[9];
    const float* b2     = (const float*)d_in[10];
    const float* Wfc    = (const float*)d_in[11];
    const float* bfc    = (const float*)d_in[12];
    float* out = (float*)d_out;

    char* w = (char*)d_ws;
    size_t off = 0;
    auto take = [&](size_t b) {
        char* p = w + off;
        off += b;
        off = (off + 255) & ~(size_t)255;
        return p;
    };
    int* bcnt   = (int*)take((size_t)NB * 4);
    int* bbase  = (int*)take((size_t)NB * 4);
    int* offs4  = (int*)take(((size_t)NK + 1) * 4);
    u32* bpack  = (u32*)take((size_t)NB * CAPB * 4);
    int* spack  = (int*)take((size_t)NE * 4);
    u16* xh     = (u16*)take((size_t)NN * FD * 2);
    u16* h1     = (u16*)take((size_t)NN * FD * 2);
    u16* Bt1    = (u16*)take((size_t)FD * KT * 2);
    u16* Bt2    = (u16*)take((size_t)FD * KT * 2);
    u16* A2     = (u16*)take((size_t)2 * NQ * KT * 2);
    float* h2q  = (float*)take((size_t)2 * NQ * FD * 4);

    hipMemsetAsync(bcnt, 0, (size_t)NB * 4, stream);
    cvt_bf16<<<((NN * FD / 4) + 255) / 256, 256, 0, stream>>>(x, xh, NN * FD);
    prep_B<<<(FD * KT + 255) / 256, 256, 0, stream>>>(Wrel1, Wroot1, Bt1);
    prep_B<<<(FD * KT + 255) / 256, 256, 0, stream>>>(Wrel2, Wroot2, Bt2);
    bucket_scatter<<<NBLK1, 256, 0, stream>>>(ei, et, bcnt, bpack);
    bucket_scan<<<1, 512, 0, stream>>>(bcnt, bbase, offs4);
    key_scatter<<<NB, 256, 0, stream>>>(bcnt, bbase, bpack, offs4, spack);

    rgcn_l1_fused<<<NBLKF, 256, 0, stream>>>(offs4, spack, (const u32*)xh, Bt1, b1, h1);

    agg_q<<<(2 * NQ + 3) / 4, 256, 0, stream>>>(offs4, spack, (const u32*)h1, A2, nest, food);
    gemm640<<<(2 * NQ + 127) / 128, 256, 0, stream>>>(A2, Bt2, b2, h2q, 2 * NQ);
    fc_kernel<<<NQ, 256, 0, stream>>>(h2q, Wfc, bfc, out);
}

// Round 5
// 313.206 us; speedup vs baseline: 1.5055x; 1.5055x over previous
//
#include <hip/hip_runtime.h>
#include <stdint.h>

#define NN 100000
#define NE 1600000
#define NR 4
#define NK (NN * NR)      // 400000 (dst,rel) keys
#define FD 128
#define KA 512            // A matrix cols (rel blocks only; root handled separately)
#define KT 640
#define NQ 1024
#define HIDN 256

#define NB 391            // dst buckets of 256 nodes
#define BSH 8
#define CAPB 8192
#define EPB 2048
#define NBLK1 ((NE + EPB - 1) / EPB)   // 782
#define MPAD 100096                    // NN rounded up to 128

using u16 = unsigned short;
using u32 = unsigned int;
typedef __attribute__((ext_vector_type(8))) __bf16 bf16x8;
typedef __attribute__((ext_vector_type(4))) float f32x4;

__device__ __forceinline__ u16 f2b(float f) {
    u32 u = __builtin_bit_cast(u32, f);
    u32 r = u + 0x7FFFu + ((u >> 16) & 1u);   // round-to-nearest-even
    return (u16)(r >> 16);
}
__device__ __forceinline__ float b2f(u16 h) {
    u32 u = ((u32)h) << 16;
    return __builtin_bit_cast(float, u);
}
__device__ __forceinline__ u32 pack2(float a, float b) {
    return (u32)f2b(a) | ((u32)f2b(b) << 16);
}
__device__ __forceinline__ bf16x8 ntload8(const u16* p) {
    return __builtin_nontemporal_load(reinterpret_cast<const bf16x8*>(p));
}

// ---------- phase 1: bucket scatter into fixed-capacity bucket-major segments ----------
__global__ __launch_bounds__(256) void bucket_scatter(const int* __restrict__ ei,
                                                      const int* __restrict__ et,
                                                      int* __restrict__ bcnt,
                                                      u32* __restrict__ bpack) {
    __shared__ int hist[NB];
    __shared__ int base[NB];
    int t = threadIdx.x;
    for (int i = t; i < NB; i += 256) hist[i] = 0;
    __syncthreads();
    int e0 = blockIdx.x * EPB;
    int rank[8];
    u32 pk[8];
    int bk[8];
#pragma unroll
    for (int j = 0; j < 8; ++j) {
        int e = e0 + j * 256 + t;
        bk[j] = -1;
        if (e < NE) {
            int src = __builtin_nontemporal_load(ei + e);
            int dst = __builtin_nontemporal_load(ei + NE + e);
            int r   = __builtin_nontemporal_load(et + e);
            bk[j] = dst >> BSH;
            pk[j] = (u32)src | ((u32)r << 17) | ((u32)(dst & 255) << 19);
            rank[j] = atomicAdd(&hist[bk[j]], 1);
        }
    }
    __syncthreads();
    for (int i = t; i < NB; i += 256) {
        int h = hist[i];
        base[i] = h ? atomicAdd(&bcnt[i], h) : 0;
    }
    __syncthreads();
#pragma unroll
    for (int j = 0; j < 8; ++j)
        if (bk[j] >= 0) bpack[(size_t)bk[j] * CAPB + base[bk[j]] + rank[j]] = pk[j];
}

// ---------- exclusive scan of bucket counts ----------
__global__ __launch_bounds__(512) void bucket_scan(const int* __restrict__ bcnt,
                                                   int* __restrict__ bbase,
                                                   int* __restrict__ offs4) {
    __shared__ int sm[512];
    int t = threadIdx.x;
    int v = (t < NB) ? bcnt[t] : 0;
    sm[t] = v;
    __syncthreads();
    for (int o2 = 1; o2 < 512; o2 <<= 1) {
        int n = (t >= o2) ? sm[t - o2] : 0;
        __syncthreads();
        sm[t] += n;
        __syncthreads();
    }
    if (t < NB) bbase[t] = sm[t] - v;
    if (t == 0) offs4[NK] = NE;
}

// ---------- phase 2: per-bucket key sort; also emits offs4 ----------
__global__ __launch_bounds__(256) void key_scatter(const int* __restrict__ bcnt,
                                                   const int* __restrict__ bbase,
                                                   const u32* __restrict__ bpack,
                                                   int* __restrict__ offs4,
                                                   int* __restrict__ spack) {
    __shared__ int hist[1024];
    __shared__ int sm[256];
    int b = blockIdx.x, t = threadIdx.x;
    int cnt = bcnt[b];
    int gbase = bbase[b];
    const u32* seg = bpack + (size_t)b * CAPB;
#pragma unroll
    for (int j = 0; j < 4; ++j) hist[t + j * 256] = 0;
    __syncthreads();
    for (int i = t; i < cnt; i += 256) {
        u32 pk = seg[i];
        atomicAdd(&hist[pk >> 17], 1);
    }
    __syncthreads();
    int t4 = t * 4;
    int h0 = hist[t4], h1 = hist[t4 + 1], h2 = hist[t4 + 2], h3 = hist[t4 + 3];
    int s = h0 + h1 + h2 + h3;
    sm[t] = s;
    __syncthreads();
    for (int o2 = 1; o2 < 256; o2 <<= 1) {
        int n = (t >= o2) ? sm[t - o2] : 0;
        __syncthreads();
        sm[t] += n;
        __syncthreads();
    }
    int e0 = gbase + sm[t] - s;
    int e1 = e0 + h0, e2 = e1 + h1, e3 = e2 + h2;
    int k0 = b << 10;
    if (k0 + t4 + 0 < NK) offs4[k0 + t4 + 0] = e0;
    if (k0 + t4 + 1 < NK) offs4[k0 + t4 + 1] = e1;
    if (k0 + t4 + 2 < NK) offs4[k0 + t4 + 2] = e2;
    if (k0 + t4 + 3 < NK) offs4[k0 + t4 + 3] = e3;
    hist[t4] = e0; hist[t4 + 1] = e1; hist[t4 + 2] = e2; hist[t4 + 3] = e3;
    __syncthreads();
    for (int i = t; i < cnt; i += 256) {
        u32 pk = seg[i];
        int pos = atomicAdd(&hist[pk >> 17], 1);
        spack[pos] = (int)(pk & 0x1FFFFu);
    }
}

// ---------- conversions / weight prep ----------
__global__ __launch_bounds__(256) void cvt_bf16(const float* __restrict__ in,
                                                u16* __restrict__ outp, int n) {
    int i = blockIdx.x * 256 + threadIdx.x;
    int idx = i * 4;
    if (idx + 3 >= n) {
        for (int j = idx; j < n; ++j) outp[j] = f2b(in[j]);
        return;
    }
    float4 v = *(const float4*)(in + idx);
    u32 lo = (u32)f2b(v.x) | ((u32)f2b(v.y) << 16);
    u32 hi = (u32)f2b(v.z) | ((u32)f2b(v.w) << 16);
    *(uint2*)(outp + idx) = make_uint2(lo, hi);
}

__global__ __launch_bounds__(256) void prep_B(const float* __restrict__ Wrel,
                                              const float* __restrict__ Wroot,
                                              u16* __restrict__ Bt) {
    int i = blockIdx.x * 256 + threadIdx.x;
    if (i >= FD * KT) return;
    int k = i % KT;
    int o = i / KT;
    float v = (k < 512) ? Wrel[(size_t)k * FD + o] : Wroot[(size_t)(k - 512) * FD + o];
    Bt[i] = f2b(v);
}

// ---------- aggregation: one wave per output row (rel blocks only, 512 cols) ----------
__global__ __launch_bounds__(256) void agg_kernel(const int* __restrict__ offs4,
                                                  const int* __restrict__ spack,
                                                  const u32* __restrict__ fp,   // feat as u32[node][64]
                                                  u16* __restrict__ Aout,
                                                  int rows,
                                                  const int* __restrict__ nest,
                                                  const int* __restrict__ food,
                                                  int qmode,
                                                  int* __restrict__ qnodes) {
    int wid = threadIdx.x >> 6, lane = threadIdx.x & 63;
    int row = blockIdx.x * 4 + wid;
    if (row >= rows) return;
    int node;
    if (qmode) node = (row < NQ) ? nest[row] : food[row - NQ];
    else node = row;
    if (qmode && lane == 0) qnodes[row] = node;

    int o0 = offs4[node * 4 + 0];
    int o1 = offs4[node * 4 + 1];
    int o2 = offs4[node * 4 + 2];
    int o3 = offs4[node * 4 + 3];
    int o4 = offs4[node * 4 + 4];

    float a00 = 0, a01 = 0, a10 = 0, a11 = 0, a20 = 0, a21 = 0, a30 = 0, a31 = 0;

#define ACCJ(IDX, V)                                             \
    {                                                            \
        float w0 = b2f((u16)((V) & 0xFFFFu));                    \
        float w1 = b2f((u16)((V) >> 16));                        \
        int _ix = (IDX);                                         \
        if (_ix < o1)      { a00 += w0; a01 += w1; }             \
        else if (_ix < o2) { a10 += w0; a11 += w1; }             \
        else if (_ix < o3) { a20 += w0; a21 += w1; }             \
        else               { a30 += w0; a31 += w1; }             \
    }

    int i = o0;
    for (; i + 8 <= o4; i += 8) {
        int p0 = spack[i + 0], p1 = spack[i + 1], p2 = spack[i + 2], p3 = spack[i + 3];
        int p4 = spack[i + 4], p5 = spack[i + 5], p6 = spack[i + 6], p7 = spack[i + 7];
        u32 v0 = fp[(size_t)p0 * 64 + lane];
        u32 v1 = fp[(size_t)p1 * 64 + lane];
        u32 v2 = fp[(size_t)p2 * 64 + lane];
        u32 v3 = fp[(size_t)p3 * 64 + lane];
        u32 v4 = fp[(size_t)p4 * 64 + lane];
        u32 v5 = fp[(size_t)p5 * 64 + lane];
        u32 v6 = fp[(size_t)p6 * 64 + lane];
        u32 v7 = fp[(size_t)p7 * 64 + lane];
        ACCJ(i + 0, v0); ACCJ(i + 1, v1); ACCJ(i + 2, v2); ACCJ(i + 3, v3);
        ACCJ(i + 4, v4); ACCJ(i + 5, v5); ACCJ(i + 6, v6); ACCJ(i + 7, v7);
    }
    for (; i < o4; ++i) {
        int p = spack[i];
        u32 v = fp[(size_t)p * 64 + lane];
        ACCJ(i, v);
    }
#undef ACCJ

    int d0 = o1 - o0, d1 = o2 - o1, d2 = o3 - o2, d3 = o4 - o3;
    float s0 = 1.0f / (float)(d0 > 1 ? d0 : 1);
    float s1 = 1.0f / (float)(d1 > 1 ? d1 : 1);
    float s2 = 1.0f / (float)(d2 > 1 ? d2 : 1);
    float s3 = 1.0f / (float)(d3 > 1 ? d3 : 1);
    u16* Ao = Aout + (size_t)row * KA + lane * 2;
    __builtin_nontemporal_store(pack2(a00 * s0, a01 * s0), (u32*)(Ao + 0));
    __builtin_nontemporal_store(pack2(a10 * s1, a11 * s1), (u32*)(Ao + 128));
    __builtin_nontemporal_store(pack2(a20 * s2, a21 * s2), (u32*)(Ao + 256));
    __builtin_nontemporal_store(pack2(a30 * s3, a31 * s3), (u32*)(Ao + 384));
}

// ---------- GEMM, no LDS: direct-fragment loads ----------
// C[M,128] = act([A[M,512] | root[M,128]] @ Bt^T + bias)
// root row r comes from rootSrc[rootIdx?rootIdx[r]:r][0..127].
__global__ __launch_bounds__(256) void gemm_direct(const u16* __restrict__ A,
                                                   const u16* __restrict__ rootSrc,
                                                   const int* __restrict__ rootIdx,
                                                   const u16* __restrict__ Bt,
                                                   const float* __restrict__ bias,
                                                   void* __restrict__ Cout,
                                                   int M, int relu, int outBf16) {
    int tid = threadIdx.x;
    int wid = tid >> 6, lane = tid & 63;
    int wm = wid >> 1, wn = wid & 1;
    int lr = lane & 15, hi = lane >> 4;
    int row0 = blockIdx.x * 128;

    f32x4 acc[4][4];
#pragma unroll
    for (int i = 0; i < 4; ++i)
#pragma unroll
        for (int j = 0; j < 4; ++j) acc[i][j] = (f32x4){0.f, 0.f, 0.f, 0.f};

    const u16* arow[4];
#pragma unroll
    for (int mi = 0; mi < 4; ++mi)
        arow[mi] = A + (size_t)(row0 + wm * 64 + mi * 16 + lr) * KA + hi * 8;

    // rel-block K steps (k = 0..511)
#pragma unroll 2
    for (int t = 0; t < 16; ++t) {
        int k0 = t * 32;
        bf16x8 afr[4], bfr[4];
#pragma unroll
        for (int ni = 0; ni < 4; ++ni) {
            int col = wn * 64 + ni * 16 + lr;
            bfr[ni] = *reinterpret_cast<const bf16x8*>(Bt + (size_t)col * KT + k0 + hi * 8);
        }
#pragma unroll
        for (int mi = 0; mi < 4; ++mi)
            afr[mi] = ntload8(arow[mi] + k0);
#pragma unroll
        for (int mi = 0; mi < 4; ++mi)
#pragma unroll
            for (int ni = 0; ni < 4; ++ni)
                acc[mi][ni] = __builtin_amdgcn_mfma_f32_16x16x32_bf16(afr[mi], bfr[ni], acc[mi][ni], 0, 0, 0);
    }

    // root K steps (k = 512..639)
    const u16* rrow[4];
#pragma unroll
    for (int mi = 0; mi < 4; ++mi) {
        int r = row0 + wm * 64 + mi * 16 + lr;
        int idx = rootIdx ? rootIdx[r] : r;
        rrow[mi] = rootSrc + (size_t)idx * FD + hi * 8;
    }
#pragma unroll
    for (int t = 0; t < 4; ++t) {
        int k0 = t * 32;
        bf16x8 afr[4], bfr[4];
#pragma unroll
        for (int ni = 0; ni < 4; ++ni) {
            int col = wn * 64 + ni * 16 + lr;
            bfr[ni] = *reinterpret_cast<const bf16x8*>(Bt + (size_t)col * KT + 512 + k0 + hi * 8);
        }
#pragma unroll
        for (int mi = 0; mi < 4; ++mi)
            afr[mi] = *reinterpret_cast<const bf16x8*>(rrow[mi] + k0);
#pragma unroll
        for (int mi = 0; mi < 4; ++mi)
#pragma unroll
            for (int ni = 0; ni < 4; ++ni)
                acc[mi][ni] = __builtin_amdgcn_mfma_f32_16x16x32_bf16(afr[mi], bfr[ni], acc[mi][ni], 0, 0, 0);
    }

    // epilogue: D col = lane&15, row = 4*(lane>>4)+reg
#pragma unroll
    for (int mi = 0; mi < 4; ++mi) {
#pragma unroll
        for (int ni = 0; ni < 4; ++ni) {
            int col = wn * 64 + ni * 16 + lr;
            float bv = bias[col];
#pragma unroll
            for (int rg = 0; rg < 4; ++rg) {
                int row = row0 + wm * 64 + mi * 16 + hi * 4 + rg;
                if (row < M) {
                    float v = acc[mi][ni][rg] + bv;
                    if (relu) v = fmaxf(v, 0.f);
                    if (outBf16) ((u16*)Cout)[(size_t)row * FD + col] = f2b(v);
                    else ((float*)Cout)[(size_t)row * FD + col] = v;
                }
            }
        }
    }
}

// ---------- final FC ----------
__global__ __launch_bounds__(256) void fc_kernel(const float* __restrict__ h2q,
                                                 const float* __restrict__ Wfc,
                                                 const float* __restrict__ bfc,
                                                 float* __restrict__ out) {
    __shared__ float comb[2 * FD];
    int q = blockIdx.x, t = threadIdx.x;
    if (t < FD) comb[t] = h2q[(size_t)q * FD + t];
    else comb[t] = h2q[(size_t)(NQ + q) * FD + (t - FD)];
    __syncthreads();
    float s = bfc[t];
#pragma unroll 4
    for (int k = 0; k < 2 * FD; ++k) s += comb[k] * Wfc[(size_t)k * HIDN + t];
    out[(size_t)q * HIDN + t] = fmaxf(s, 0.f);
}

extern "C" void kernel_launch(void* const* d_in, const int* in_sizes, int n_in,
                              void* d_out, int out_size, void* d_ws, size_t ws_size,
                              hipStream_t stream) {
    const float* x      = (const float*)d_in[0];
    const int*   ei     = (const int*)d_in[1];
    const int*   et     = (const int*)d_in[2];
    const int*   nest   = (const int*)d_in[3];
    const int*   food   = (const int*)d_in[4];
    const float* Wrel1  = (const float*)d_in[5];
    const float* Wroot1 = (const float*)d_in[6];
    const float* b1     = (const float*)d_in[7];
    const float* Wrel2  = (const float*)d_in[8];
    const float* Wroot2 = (const float*)d_in[9];
    const float* b2     = (const float*)d_in[10];
    const float* Wfc    = (const float*)d_in[11];
    const float* bfc    = (const float*)d_in[12];
    float* out = (float*)d_out;

    char* w = (char*)d_ws;
    size_t off = 0;
    auto take = [&](size_t b) {
        char* p = w + off;
        off += b;
        off = (off + 255) & ~(size_t)255;
        return p;
    };
    int* bcnt   = (int*)take((size_t)NB * 4);
    int* bbase  = (int*)take((size_t)NB * 4);
    int* offs4  = (int*)take(((size_t)NK + 1) * 4);
    u32* bpack  = (u32*)take((size_t)NB * CAPB * 4);
    int* spack  = (int*)take((size_t)NE * 4);
    int* qnodes = (int*)take((size_t)2 * NQ * 4);
    u16* xh     = (u16*)take((size_t)MPAD * FD * 2);   // padded to 100096 rows
    u16* h1     = (u16*)take((size_t)NN * FD * 2);
    u16* Bt1    = (u16*)take((size_t)FD * KT * 2);
    u16* Bt2    = (u16*)take((size_t)FD * KT * 2);
    u16* A1     = (u16*)take((size_t)MPAD * KA * 2);   // padded rows for direct-fragment loads
    u16* A2     = (u16*)take((size_t)2 * NQ * KA * 2);
    float* h2q  = (float*)take((size_t)2 * NQ * FD * 4);

    hipMemsetAsync(bcnt, 0, (size_t)NB * 4, stream);
    cvt_bf16<<<((NN * FD / 4) + 255) / 256, 256, 0, stream>>>(x, xh, NN * FD);
    prep_B<<<(FD * KT + 255) / 256, 256, 0, stream>>>(Wrel1, Wroot1, Bt1);
    prep_B<<<(FD * KT + 255) / 256, 256, 0, stream>>>(Wrel2, Wroot2, Bt2);
    bucket_scatter<<<NBLK1, 256, 0, stream>>>(ei, et, bcnt, bpack);
    bucket_scan<<<1, 512, 0, stream>>>(bcnt, bbase, offs4);
    key_scatter<<<NB, 256, 0, stream>>>(bcnt, bbase, bpack, offs4, spack);

    agg_kernel<<<(NN + 3) / 4, 256, 0, stream>>>(offs4, spack, (const u32*)xh, A1,
                                                 NN, nullptr, nullptr, 0, nullptr);
    gemm_direct<<<(NN + 127) / 128, 256, 0, stream>>>(A1, xh, nullptr, Bt1, b1,
                                                      (void*)h1, NN, 1, 1);

    agg_kernel<<<(2 * NQ + 3) / 4, 256, 0, stream>>>(offs4, spack, (const u32*)h1, A2,
                                                     2 * NQ, nest, food, 1, qnodes);
    gemm_direct<<<(2 * NQ + 127) / 128, 256, 0, stream>>>(A2, h1, qnodes, Bt2, b2,
                                                          (void*)h2q, 2 * NQ, 0, 0);
    fc_kernel<<<NQ, 256, 0, stream>>>(h2q, Wfc, bfc, out);
}

// Round 6
// 301.146 us; speedup vs baseline: 1.5658x; 1.0400x over previous
//
#include <hip/hip_runtime.h>
#include <stdint.h>

#define NN 100000
#define NE 1600000
#define NR 4
#define NK (NN * NR)      // 400000 (dst,rel) keys
#define FD 128
#define KA 512            // A matrix cols (rel blocks only; root handled separately)
#define KT 640
#define NQ 1024
#define HIDN 256

#define NB 391            // dst buckets of 256 nodes
#define BSH 8
#define CAPB 8192
#define EPB 2048
#define NBLK1 ((NE + EPB - 1) / EPB)   // 782
#define MPAD 100096                    // NN rounded up to 128

using u16 = unsigned short;
using u32 = unsigned int;
typedef __attribute__((ext_vector_type(8))) __bf16 bf16x8;
typedef __attribute__((ext_vector_type(4))) float f32x4;

__device__ __forceinline__ u16 f2b(float f) {
    u32 u = __builtin_bit_cast(u32, f);
    u32 r = u + 0x7FFFu + ((u >> 16) & 1u);   // round-to-nearest-even
    return (u16)(r >> 16);
}
__device__ __forceinline__ float b2f(u16 h) {
    u32 u = ((u32)h) << 16;
    return __builtin_bit_cast(float, u);
}
__device__ __forceinline__ u32 pack2(float a, float b) {
    return (u32)f2b(a) | ((u32)f2b(b) << 16);
}
__device__ __forceinline__ bf16x8 ntload8(const u16* p) {
    return __builtin_nontemporal_load(reinterpret_cast<const bf16x8*>(p));
}

// ---------- phase 1: bucket scatter into fixed-capacity bucket-major segments ----------
__global__ __launch_bounds__(256) void bucket_scatter(const int* __restrict__ ei,
                                                      const int* __restrict__ et,
                                                      int* __restrict__ bcnt,
                                                      u32* __restrict__ bpack) {
    __shared__ int hist[NB];
    __shared__ int base[NB];
    int t = threadIdx.x;
    for (int i = t; i < NB; i += 256) hist[i] = 0;
    __syncthreads();
    int e0 = blockIdx.x * EPB;
    int rank[8];
    u32 pk[8];
    int bk[8];
#pragma unroll
    for (int j = 0; j < 8; ++j) {
        int e = e0 + j * 256 + t;
        bk[j] = -1;
        if (e < NE) {
            int src = __builtin_nontemporal_load(ei + e);
            int dst = __builtin_nontemporal_load(ei + NE + e);
            int r   = __builtin_nontemporal_load(et + e);
            bk[j] = dst >> BSH;
            pk[j] = (u32)src | ((u32)r << 17) | ((u32)(dst & 255) << 19);
            rank[j] = atomicAdd(&hist[bk[j]], 1);
        }
    }
    __syncthreads();
    for (int i = t; i < NB; i += 256) {
        int h = hist[i];
        base[i] = h ? atomicAdd(&bcnt[i], h) : 0;
    }
    __syncthreads();
#pragma unroll
    for (int j = 0; j < 8; ++j)
        if (bk[j] >= 0) bpack[(size_t)bk[j] * CAPB + base[bk[j]] + rank[j]] = pk[j];
}

// ---------- exclusive scan of bucket counts ----------
__global__ __launch_bounds__(512) void bucket_scan(const int* __restrict__ bcnt,
                                                   int* __restrict__ bbase,
                                                   int* __restrict__ offs4) {
    __shared__ int sm[512];
    int t = threadIdx.x;
    int v = (t < NB) ? bcnt[t] : 0;
    sm[t] = v;
    __syncthreads();
    for (int o2 = 1; o2 < 512; o2 <<= 1) {
        int n = (t >= o2) ? sm[t - o2] : 0;
        __syncthreads();
        sm[t] += n;
        __syncthreads();
    }
    if (t < NB) bbase[t] = sm[t] - v;
    if (t == 0) offs4[NK] = NE;
}

// ---------- phase 2: per-bucket key sort; also emits offs4 ----------
__global__ __launch_bounds__(256) void key_scatter(const int* __restrict__ bcnt,
                                                   const int* __restrict__ bbase,
                                                   const u32* __restrict__ bpack,
                                                   int* __restrict__ offs4,
                                                   int* __restrict__ spack) {
    __shared__ int hist[1024];
    __shared__ int sm[256];
    int b = blockIdx.x, t = threadIdx.x;
    int cnt = bcnt[b];
    int gbase = bbase[b];
    const u32* seg = bpack + (size_t)b * CAPB;
#pragma unroll
    for (int j = 0; j < 4; ++j) hist[t + j * 256] = 0;
    __syncthreads();
    for (int i = t; i < cnt; i += 256) {
        u32 pk = seg[i];
        atomicAdd(&hist[pk >> 17], 1);
    }
    __syncthreads();
    int t4 = t * 4;
    int h0 = hist[t4], h1 = hist[t4 + 1], h2 = hist[t4 + 2], h3 = hist[t4 + 3];
    int s = h0 + h1 + h2 + h3;
    sm[t] = s;
    __syncthreads();
    for (int o2 = 1; o2 < 256; o2 <<= 1) {
        int n = (t >= o2) ? sm[t - o2] : 0;
        __syncthreads();
        sm[t] += n;
        __syncthreads();
    }
    int e0 = gbase + sm[t] - s;
    int e1 = e0 + h0, e2 = e1 + h1, e3 = e2 + h2;
    int k0 = b << 10;
    if (k0 + t4 + 0 < NK) offs4[k0 + t4 + 0] = e0;
    if (k0 + t4 + 1 < NK) offs4[k0 + t4 + 1] = e1;
    if (k0 + t4 + 2 < NK) offs4[k0 + t4 + 2] = e2;
    if (k0 + t4 + 3 < NK) offs4[k0 + t4 + 3] = e3;
    hist[t4] = e0; hist[t4 + 1] = e1; hist[t4 + 2] = e2; hist[t4 + 3] = e3;
    __syncthreads();
    for (int i = t; i < cnt; i += 256) {
        u32 pk = seg[i];
        int pos = atomicAdd(&hist[pk >> 17], 1);
        spack[pos] = (int)(pk & 0x1FFFFu);
    }
}

// ---------- conversions / weight prep ----------
__global__ __launch_bounds__(256) void cvt_bf16(const float* __restrict__ in,
                                                u16* __restrict__ outp, int n) {
    int i = blockIdx.x * 256 + threadIdx.x;
    int idx = i * 4;
    if (idx + 3 >= n) {
        for (int j = idx; j < n; ++j) outp[j] = f2b(in[j]);
        return;
    }
    float4 v = *(const float4*)(in + idx);
    u32 lo = (u32)f2b(v.x) | ((u32)f2b(v.y) << 16);
    u32 hi = (u32)f2b(v.z) | ((u32)f2b(v.w) << 16);
    *(uint2*)(outp + idx) = make_uint2(lo, hi);
}

__global__ __launch_bounds__(256) void prep_B(const float* __restrict__ Wrel,
                                              const float* __restrict__ Wroot,
                                              u16* __restrict__ Bt) {
    int i = blockIdx.x * 256 + threadIdx.x;
    if (i >= FD * KT) return;
    int k = i % KT;
    int o = i / KT;
    float v = (k < 512) ? Wrel[(size_t)k * FD + o] : Wroot[(size_t)(k - 512) * FD + o];
    Bt[i] = f2b(v);
}

// ---------- aggregation: one wave per output row (rel blocks only, 512 cols) ----------
__global__ __launch_bounds__(256) void agg_kernel(const int* __restrict__ offs4,
                                                  const int* __restrict__ spack,
                                                  const u32* __restrict__ fp,   // feat as u32[node][64]
                                                  u16* __restrict__ Aout,
                                                  int rows,
                                                  const int* __restrict__ nest,
                                                  const int* __restrict__ food,
                                                  int qmode,
                                                  int* __restrict__ qnodes) {
    int wid = threadIdx.x >> 6, lane = threadIdx.x & 63;
    int row = blockIdx.x * 4 + wid;
    if (row >= rows) return;
    int node;
    if (qmode) node = (row < NQ) ? nest[row] : food[row - NQ];
    else node = row;
    if (qmode && lane == 0) qnodes[row] = node;

    int o0 = offs4[node * 4 + 0];
    int o1 = offs4[node * 4 + 1];
    int o2 = offs4[node * 4 + 2];
    int o3 = offs4[node * 4 + 3];
    int o4 = offs4[node * 4 + 4];

    float a00 = 0, a01 = 0, a10 = 0, a11 = 0, a20 = 0, a21 = 0, a30 = 0, a31 = 0;

#define ACCJ(IDX, V)                                             \
    {                                                            \
        float w0 = b2f((u16)((V) & 0xFFFFu));                    \
        float w1 = b2f((u16)((V) >> 16));                        \
        int _ix = (IDX);                                         \
        if (_ix < o1)      { a00 += w0; a01 += w1; }             \
        else if (_ix < o2) { a10 += w0; a11 += w1; }             \
        else if (_ix < o3) { a20 += w0; a21 += w1; }             \
        else               { a30 += w0; a31 += w1; }             \
    }

    int i = o0;
    for (; i + 8 <= o4; i += 8) {
        int p0 = spack[i + 0], p1 = spack[i + 1], p2 = spack[i + 2], p3 = spack[i + 3];
        int p4 = spack[i + 4], p5 = spack[i + 5], p6 = spack[i + 6], p7 = spack[i + 7];
        u32 v0 = fp[(size_t)p0 * 64 + lane];
        u32 v1 = fp[(size_t)p1 * 64 + lane];
        u32 v2 = fp[(size_t)p2 * 64 + lane];
        u32 v3 = fp[(size_t)p3 * 64 + lane];
        u32 v4 = fp[(size_t)p4 * 64 + lane];
        u32 v5 = fp[(size_t)p5 * 64 + lane];
        u32 v6 = fp[(size_t)p6 * 64 + lane];
        u32 v7 = fp[(size_t)p7 * 64 + lane];
        ACCJ(i + 0, v0); ACCJ(i + 1, v1); ACCJ(i + 2, v2); ACCJ(i + 3, v3);
        ACCJ(i + 4, v4); ACCJ(i + 5, v5); ACCJ(i + 6, v6); ACCJ(i + 7, v7);
    }
    for (; i < o4; ++i) {
        int p = spack[i];
        u32 v = fp[(size_t)p * 64 + lane];
        ACCJ(i, v);
    }
#undef ACCJ

    int d0 = o1 - o0, d1 = o2 - o1, d2 = o3 - o2, d3 = o4 - o3;
    float s0 = 1.0f / (float)(d0 > 1 ? d0 : 1);
    float s1 = 1.0f / (float)(d1 > 1 ? d1 : 1);
    float s2 = 1.0f / (float)(d2 > 1 ? d2 : 1);
    float s3 = 1.0f / (float)(d3 > 1 ? d3 : 1);
    // plain (temporal) stores: keep A in L2/L3 for the GEMM that follows
    u16* Ao = Aout + (size_t)row * KA + lane * 2;
    *(u32*)(Ao + 0)   = pack2(a00 * s0, a01 * s0);
    *(u32*)(Ao + 128) = pack2(a10 * s1, a11 * s1);
    *(u32*)(Ao + 256) = pack2(a20 * s2, a21 * s2);
    *(u32*)(Ao + 384) = pack2(a30 * s3, a31 * s3);
}

// ---------- GEMM, no LDS, software-pipelined direct-fragment loads ----------
// C[M,128] = act([A[M,512] | root[M,128]] @ Bt^T + bias)
// 20 K-steps of 32: steps 0..15 from A, 16..19 from rootSrc (gathered rows).
// A prefetched 2 steps ahead (3-stage), B 1 step ahead (2-stage).
__global__ __launch_bounds__(256, 3) void gemm_direct(const u16* __restrict__ A,
                                                      const u16* __restrict__ rootSrc,
                                                      const int* __restrict__ rootIdx,
                                                      const u16* __restrict__ Bt,
                                                      const float* __restrict__ bias,
                                                      void* __restrict__ Cout,
                                                      int M, int relu, int outBf16) {
    int tid = threadIdx.x;
    int wid = tid >> 6, lane = tid & 63;
    int wm = wid >> 1, wn = wid & 1;
    int lr = lane & 15, hi = lane >> 4;
    int row0 = blockIdx.x * 128;

    f32x4 acc[4][4];
#pragma unroll
    for (int i = 0; i < 4; ++i)
#pragma unroll
        for (int j = 0; j < 4; ++j) acc[i][j] = (f32x4){0.f, 0.f, 0.f, 0.f};

    const u16* arow[4];
    const u16* rrow[4];
    const u16* brow[4];
#pragma unroll
    for (int mi = 0; mi < 4; ++mi) {
        int r = row0 + wm * 64 + mi * 16 + lr;
        arow[mi] = A + (size_t)r * KA + hi * 8;
        int idx = rootIdx ? rootIdx[r] : r;
        rrow[mi] = rootSrc + (size_t)idx * FD + hi * 8;
    }
#pragma unroll
    for (int ni = 0; ni < 4; ++ni) {
        int col = wn * 64 + ni * 16 + lr;
        brow[ni] = Bt + (size_t)col * KT + hi * 8;
    }

    bf16x8 aS[3][4];   // 3-stage A pipeline
    bf16x8 bS[2][4];   // 2-stage B pipeline

    auto loadA = [&](int t, bf16x8* dst) {
#pragma unroll
        for (int mi = 0; mi < 4; ++mi)
            dst[mi] = (t < 16) ? ntload8(arow[mi] + t * 32)
                               : *reinterpret_cast<const bf16x8*>(rrow[mi] + (t - 16) * 32);
    };
    auto loadB = [&](int t, bf16x8* dst) {
#pragma unroll
        for (int ni = 0; ni < 4; ++ni)
            dst[ni] = *reinterpret_cast<const bf16x8*>(brow[ni] + t * 32);
    };

    loadA(0, aS[0]);
    loadA(1, aS[1]);
    loadB(0, bS[0]);

#pragma unroll
    for (int t = 0; t < 20; ++t) {
        if (t + 2 < 20) loadA(t + 2, aS[(t + 2) % 3]);
        if (t + 1 < 20) loadB(t + 1, bS[(t + 1) % 2]);
        bf16x8* af = aS[t % 3];
        bf16x8* bf = bS[t % 2];
#pragma unroll
        for (int mi = 0; mi < 4; ++mi)
#pragma unroll
            for (int ni = 0; ni < 4; ++ni)
                acc[mi][ni] = __builtin_amdgcn_mfma_f32_16x16x32_bf16(af[mi], bf[ni], acc[mi][ni], 0, 0, 0);
    }

    // epilogue: D col = lane&15, row = 4*(lane>>4)+reg
#pragma unroll
    for (int mi = 0; mi < 4; ++mi) {
#pragma unroll
        for (int ni = 0; ni < 4; ++ni) {
            int col = wn * 64 + ni * 16 + lr;
            float bv = bias[col];
#pragma unroll
            for (int rg = 0; rg < 4; ++rg) {
                int row = row0 + wm * 64 + mi * 16 + hi * 4 + rg;
                if (row < M) {
                    float v = acc[mi][ni][rg] + bv;
                    if (relu) v = fmaxf(v, 0.f);
                    if (outBf16) ((u16*)Cout)[(size_t)row * FD + col] = f2b(v);
                    else ((float*)Cout)[(size_t)row * FD + col] = v;
                }
            }
        }
    }
}

// ---------- final FC ----------
__global__ __launch_bounds__(256) void fc_kernel(const float* __restrict__ h2q,
                                                 const float* __restrict__ Wfc,
                                                 const float* __restrict__ bfc,
                                                 float* __restrict__ out) {
    __shared__ float comb[2 * FD];
    int q = blockIdx.x, t = threadIdx.x;
    if (t < FD) comb[t] = h2q[(size_t)q * FD + t];
    else comb[t] = h2q[(size_t)(NQ + q) * FD + (t - FD)];
    __syncthreads();
    float s = bfc[t];
#pragma unroll 4
    for (int k = 0; k < 2 * FD; ++k) s += comb[k] * Wfc[(size_t)k * HIDN + t];
    out[(size_t)q * HIDN + t] = fmaxf(s, 0.f);
}

extern "C" void kernel_launch(void* const* d_in, const int* in_sizes, int n_in,
                              void* d_out, int out_size, void* d_ws, size_t ws_size,
                              hipStream_t stream) {
    const float* x      = (const float*)d_in[0];
    const int*   ei     = (const int*)d_in[1];
    const int*   et     = (const int*)d_in[2];
    const int*   nest   = (const int*)d_in[3];
    const int*   food   = (const int*)d_in[4];
    const float* Wrel1  = (const float*)d_in[5];
    const float* Wroot1 = (const float*)d_in[6];
    const float* b1     = (const float*)d_in[7];
    const float* Wrel2  = (const float*)d_in[8];
    const float* Wroot2 = (const float*)d_in[9];
    const float* b2     = (const float*)d_in[10];
    const float* Wfc    = (const float*)d_in[11];
    const float* bfc    = (const float*)d_in[12];
    float* out = (float*)d_out;

    char* w = (char*)d_ws;
    size_t off = 0;
    auto take = [&](size_t b) {
        char* p = w + off;
        off += b;
        off = (off + 255) & ~(size_t)255;
        return p;
    };
    int* bcnt   = (int*)take((size_t)NB * 4);
    int* bbase  = (int*)take((size_t)NB * 4);
    int* offs4  = (int*)take(((size_t)NK + 1) * 4);
    u32* bpack  = (u32*)take((size_t)NB * CAPB * 4);
    int* spack  = (int*)take((size_t)NE * 4);
    int* qnodes = (int*)take((size_t)2 * NQ * 4);
    u16* xh     = (u16*)take((size_t)MPAD * FD * 2);   // padded to 100096 rows
    u16* h1     = (u16*)take((size_t)NN * FD * 2);
    u16* Bt1    = (u16*)take((size_t)FD * KT * 2);
    u16* Bt2    = (u16*)take((size_t)FD * KT * 2);
    u16* A1     = (u16*)take((size_t)MPAD * KA * 2);   // padded rows for direct-fragment loads
    u16* A2     = (u16*)take((size_t)2 * NQ * KA * 2);
    float* h2q  = (float*)take((size_t)2 * NQ * FD * 4);

    hipMemsetAsync(bcnt, 0, (size_t)NB * 4, stream);
    cvt_bf16<<<((NN * FD / 4) + 255) / 256, 256, 0, stream>>>(x, xh, NN * FD);
    prep_B<<<(FD * KT + 255) / 256, 256, 0, stream>>>(Wrel1, Wroot1, Bt1);
    prep_B<<<(FD * KT + 255) / 256, 256, 0, stream>>>(Wrel2, Wroot2, Bt2);
    bucket_scatter<<<NBLK1, 256, 0, stream>>>(ei, et, bcnt, bpack);
    bucket_scan<<<1, 512, 0, stream>>>(bcnt, bbase, offs4);
    key_scatter<<<NB, 256, 0, stream>>>(bcnt, bbase, bpack, offs4, spack);

    agg_kernel<<<(NN + 3) / 4, 256, 0, stream>>>(offs4, spack, (const u32*)xh, A1,
                                                 NN, nullptr, nullptr, 0, nullptr);
    gemm_direct<<<(NN + 127) / 128, 256, 0, stream>>>(A1, xh, nullptr, Bt1, b1,
                                                      (void*)h1, NN, 1, 1);

    agg_kernel<<<(2 * NQ + 3) / 4, 256, 0, stream>>>(offs4, spack, (const u32*)h1, A2,
                                                     2 * NQ, nest, food, 1, qnodes);
    gemm_direct<<<(2 * NQ + 127) / 128, 256, 0, stream>>>(A2, h1, qnodes, Bt2, b2,
                                                          (void*)h2q, 2 * NQ, 0, 0);
    fc_kernel<<<NQ, 256, 0, stream>>>(h2q, Wfc, bfc, out);
}